// Round 1
// 587.449 us; speedup vs baseline: 1.0015x; 1.0015x over previous
//
#include <hip/hip_runtime.h>
#include <hip/hip_bf16.h>

typedef __hip_bfloat16 bf16;
typedef __attribute__((ext_vector_type(8))) short bf16x8;
typedef __attribute__((ext_vector_type(4))) float f32x4;

#define Bn 4
#define Cn 256
#define C2n 512
#define Hn 128
#define Wn 128
#define HWn 16384
#define HEADSn 8
#define CHn 32
// padded pixel-major y tensor: [b][130 y][132 x][256 c]
#define PADW 132
#define PADH 130
#define PROW (PADW * Cn)              // 33792 elems per padded row
#define PBn ((size_t)PADH * PROW)     // elems per batch

static __device__ __forceinline__ float b2f(bf16 v) { return __bfloat162float(v); }
static __device__ __forceinline__ bf16 f2b(float v) { return __float2bfloat16(v); }
static __device__ __forceinline__ short f2bs(float v) {
    bf16 t = f2b(v);
    return __builtin_bit_cast(short, t);
}
static __device__ __forceinline__ float s2f(short s) {
    bf16 t = __builtin_bit_cast(bf16, s);
    return b2f(t);
}

// async global->LDS, 16B per lane; LDS dest = wave-uniform base + lane*16
static __device__ __forceinline__ void gload16(const void* g, void* l) {
    __builtin_amdgcn_global_load_lds(
        (const __attribute__((address_space(1))) unsigned int*)g,
        (__attribute__((address_space(3))) unsigned int*)l,
        16, 0, 0);
}

// ---------------- f32 -> bf16 cast ----------------
__global__ void cast_kernel(const float* __restrict__ src, bf16* __restrict__ dst, int n) {
    for (int i = blockIdx.x * 256 + threadIdx.x; i < n; i += gridDim.x * 256)
        dst[i] = f2b(src[i]);
}

// ---------------- repack Wq: f32 [oc][c][3][3] -> bf16 [dy][oc][dx*256+c] ----------------
__global__ void wq_repack_kernel(const float* __restrict__ Wq, bf16* __restrict__ wr) {
    int i = blockIdx.x * 256 + threadIdx.x;     // over oc*c = 65536
    if (i < Cn * Cn) {
        int oc = i >> 8, c = i & 255;
        #pragma unroll
        for (int dy = 0; dy < 3; dy++)
            #pragma unroll
            for (int dx = 0; dx < 3; dx++)
                wr[((size_t)dy * Cn + oc) * 768 + dx * Cn + c] =
                    f2b(Wq[(size_t)i * 9 + dy * 3 + dx]);
    }
}

// ---------------- zero halo of padded yn tensor ----------------
__global__ void halo_zero_kernel(bf16* __restrict__ yp) {
    int yq = blockIdx.x;           // 0..129
    int b  = blockIdx.y;
    bf16* row = yp + (size_t)b * PBn + (size_t)yq * PROW;
    bf16x8 z = {0, 0, 0, 0, 0, 0, 0, 0};
    if (yq == 0 || yq == PADH - 1) {
        for (int i = threadIdx.x; i < PROW / 8; i += 256)
            *(bf16x8*)&row[(size_t)i * 8] = z;
    } else {
        // x pad: col 0 (256 elems = 32 slots) and cols 129..131 (768 elems = 96 slots)
        for (int i = threadIdx.x; i < 128; i += 256) {
            if (i < 32) *(bf16x8*)&row[(size_t)i * 8] = z;
            else        *(bf16x8*)&row[(size_t)129 * Cn + (size_t)(i - 32) * 8] = z;
        }
    }
}

// ---------------- LayerNorm over channel dim (per pixel) ----------------
__global__ void ln_kernel(const float* __restrict__ x,
                          const float* __restrict__ gw,
                          const float* __restrict__ gb,
                          bf16* __restrict__ o16) {
    __shared__ float sw[Cn], sb[Cn];
    int tid = threadIdx.x;
    if (tid < Cn) { sw[tid] = gw[tid]; sb[tid] = gb[tid]; }
    __syncthreads();
    int pix = blockIdx.x * 256 + tid;
    int b = pix >> 14;
    int hw = pix & (HWn - 1);
    const float* xb = x + (size_t)b * Cn * HWn + hw;
    float s = 0.f, ss = 0.f;
    for (int c = 0; c < Cn; c++) {
        float v = xb[(size_t)c * HWn];
        s += v; ss += v * v;
    }
    float mu  = s * (1.f / Cn);
    float var = ss * (1.f / Cn) - mu * mu;
    float inv = rsqrtf(var + 1e-5f);
    bf16* ob = o16 + (size_t)b * Cn * HWn + hw;
    for (int c = 0; c < Cn; c++) {
        float v = (xb[(size_t)c * HWn] - mu) * inv * sw[c] + sb[c];
        ob[(size_t)c * HWn] = f2b(v);
    }
}

// ---------------- transpose: [b][c][hw] bf16 -> [b][hw][c] bf16 ----------------
__global__ void transpose_kernel(const bf16* __restrict__ src, bf16* __restrict__ dst) {
    __shared__ unsigned int t[64][65];
    int tid = threadIdx.x;
    int pxt = blockIdx.x;
    int ct  = blockIdx.y;
    int b   = blockIdx.z;
    const bf16* sb = src + ((size_t)b * Cn + ct * 64) * HWn + pxt * 64;
    for (int i = tid; i < 512; i += 256) {
        int r = i >> 3, sg = (i & 7) * 8;
        bf16x8 v = *(const bf16x8*)&sb[(size_t)r * HWn + sg];
        #pragma unroll
        for (int j = 0; j < 8; j++) t[r][sg + j] = (unsigned int)(unsigned short)v[j];
    }
    __syncthreads();
    bf16* db = dst + ((size_t)b * HWn + pxt * 64) * Cn + ct * 64;
    for (int i = tid; i < 512; i += 256) {
        int r = i >> 3, sg = (i & 7) * 8;
        bf16x8 v;
        #pragma unroll
        for (int j = 0; j < 8; j++) v[j] = (short)(unsigned short)t[sg + j][r];
        *(bf16x8*)&db[(size_t)r * Cn + sg] = v;
    }
}

// ---------------- transpose into PADDED pixel-major: [b][c][hw] -> [b][y+1][x+1][c] ----------------
__global__ void transpose_pad_kernel(const bf16* __restrict__ src, bf16* __restrict__ dst) {
    __shared__ unsigned int t[64][65];
    int tid = threadIdx.x;
    int pxt = blockIdx.x;
    int ct  = blockIdx.y;
    int b   = blockIdx.z;
    const bf16* sb = src + ((size_t)b * Cn + ct * 64) * HWn + pxt * 64;
    for (int i = tid; i < 512; i += 256) {
        int r = i >> 3, sg = (i & 7) * 8;
        bf16x8 v = *(const bf16x8*)&sb[(size_t)r * HWn + sg];
        #pragma unroll
        for (int j = 0; j < 8; j++) t[r][sg + j] = (unsigned int)(unsigned short)v[j];
    }
    __syncthreads();
    // 64 consecutive pixels of one y row (W=128, 64 | 128)
    int p0 = pxt * 64;
    int yr = p0 >> 7, x0 = p0 & 127;
    bf16* db = dst + (size_t)b * PBn
                   + ((size_t)(yr + 1) * PADW + (x0 + 1)) * Cn + ct * 64;
    for (int i = tid; i < 512; i += 256) {
        int r = i >> 3, sg = (i & 7) * 8;
        bf16x8 v;
        #pragma unroll
        for (int j = 0; j < 8; j++) v[j] = (short)(unsigned short)t[sg + j][r];
        *(bf16x8*)&db[(size_t)r * Cn + sg] = v;
    }
}

// ---------------- kv 1x1 conv as GEMM via MFMA + global_load_lds ----------------
// LDS layout per tile: [4 kq][128 r][8 shorts] -> fragment ds_read_b128 at
// consecutive addresses (conflict-free), staging is linear (gload_lds-compatible).
__global__ __launch_bounds__(256) void kv1x1_mfma_kernel(
        const bf16* __restrict__ xn_pm,    // [b][px][c]
        const bf16* __restrict__ wkv_pk,   // [oc][c] bf16 (512x256)
        bf16* __restrict__ kv) {           // [b][oc][px]
    __shared__ __attribute__((aligned(16))) short Als[4096];
    __shared__ __attribute__((aligned(16))) short Bls[4096];
    int tid  = threadIdx.x;
    int px0  = blockIdx.x * 128;
    int oc0  = blockIdx.y * 128;
    int b    = blockIdx.z;
    int wave = tid >> 6, lane = tid & 63;
    int lm = lane & 15, kq = lane >> 4;

    f32x4 acc[2][8];
    #pragma unroll
    for (int mt = 0; mt < 2; mt++)
        #pragma unroll
        for (int nt = 0; nt < 8; nt++) acc[mt][nt] = (f32x4){0.f, 0.f, 0.f, 0.f};

    int s0 = tid, s1 = tid + 256;
    int r0 = s0 & 127, kq0 = s0 >> 7;
    int r1 = s1 & 127, kq1 = s1 >> 7;
    short* lA0 = &Als[(size_t)(wave * 64) * 8];
    short* lA1 = &Als[(size_t)(256 + wave * 64) * 8];
    short* lB0 = &Bls[(size_t)(wave * 64) * 8];
    short* lB1 = &Bls[(size_t)(256 + wave * 64) * 8];

    const short* wb = (const short*)wkv_pk + (size_t)oc0 * Cn;
    const short* xb = (const short*)(xn_pm) + ((size_t)b * HWn + px0) * Cn;
    const short* wA0 = wb + (size_t)r0 * Cn + kq0 * 8;
    const short* wA1 = wb + (size_t)r1 * Cn + kq1 * 8;
    const short* xB0 = xb + (size_t)r0 * Cn + kq0 * 8;
    const short* xB1 = xb + (size_t)r1 * Cn + kq1 * 8;

    for (int kc = 0; kc < Cn; kc += 32) {
        __syncthreads();
        gload16(wA0 + kc, lA0);
        gload16(wA1 + kc, lA1);
        gload16(xB0 + kc, lB0);
        gload16(xB1 + kc, lB1);
        __syncthreads();
        bf16x8 afr[2], bfr[8];
        #pragma unroll
        for (int mt = 0; mt < 2; mt++)
            afr[mt] = *(const bf16x8*)&Als[((kq << 7) + wave * 32 + mt * 16 + lm) * 8];
        #pragma unroll
        for (int nt = 0; nt < 8; nt++)
            bfr[nt] = *(const bf16x8*)&Bls[((kq << 7) + nt * 16 + lm) * 8];
        #pragma unroll
        for (int mt = 0; mt < 2; mt++)
            #pragma unroll
            for (int nt = 0; nt < 8; nt++)
                acc[mt][nt] = __builtin_amdgcn_mfma_f32_16x16x32_bf16(
                    afr[mt], bfr[nt], acc[mt][nt], 0, 0, 0);
    }
    bf16* kb = kv + ((size_t)b * C2n + oc0) * HWn + px0;
    #pragma unroll
    for (int mt = 0; mt < 2; mt++) {
        int ocl = wave * 32 + mt * 16 + kq * 4;
        #pragma unroll
        for (int nt = 0; nt < 8; nt++) {
            int px = nt * 16 + lm;
            #pragma unroll
            for (int r = 0; r < 4; r++)
                kb[(size_t)(ocl + r) * HWn + px] = f2b(acc[mt][nt][r]);
        }
    }
}

// ---------------- depthwise 3x3 SAME, vectorized via LDS strip ----------------
__global__ void dw_kernel(const bf16* __restrict__ kv,
                          const float* __restrict__ Wdw,
                          bf16* __restrict__ kvdw) {
    __shared__ float st[18][132];
    int tid = threadIdx.x;
    int r0  = blockIdx.x * 16;
    int ch  = blockIdx.y;
    int b   = blockIdx.z;
    float w[9];
    #pragma unroll
    for (int t = 0; t < 9; t++) w[t] = Wdw[ch * 9 + t];
    const bf16* base = kv + ((size_t)b * C2n + ch) * HWn;
    if (tid < 18) { st[tid][0] = 0.f; st[tid][129] = 0.f; }
    for (int i = tid; i < 288; i += 256) {
        int row = i >> 4, sg = (i & 15) << 3;
        int gr = r0 - 1 + row;
        bf16x8 v = {0, 0, 0, 0, 0, 0, 0, 0};
        if (gr >= 0 && gr < Hn) v = *(const bf16x8*)&base[(size_t)gr * Wn + sg];
        #pragma unroll
        for (int j = 0; j < 8; j++) st[row][1 + sg + j] = s2f(v[j]);
    }
    __syncthreads();
    int orow = tid >> 4, sg = (tid & 15) << 3;
    float o[8];
    #pragma unroll
    for (int j = 0; j < 8; j++) o[j] = 0.f;
    #pragma unroll
    for (int dy = 0; dy < 3; dy++)
        #pragma unroll
        for (int dx = 0; dx < 3; dx++) {
            float ww = w[dy * 3 + dx];
            #pragma unroll
            for (int j = 0; j < 8; j++) o[j] += ww * st[orow + dy][sg + j + dx];
        }
    bf16x8 ov;
    #pragma unroll
    for (int j = 0; j < 8; j++) ov[j] = f2bs(o[j]);
    *(bf16x8*)&kvdw[((size_t)b * C2n + ch) * HWn + (size_t)(r0 + orow) * Wn + sg] = ov;
}

// ---------------- q 3x3 conv: 3 row-GEMMs with contiguous K=768 ----------------
// B[p][k] = ypad_row[p*256 + k] (k = dx*256 + c), so this is a plain GEMM:
// M=128 oc, N=128 px (one y row), K=3x768, staged via global_load_lds.
__global__ __launch_bounds__(256) void qconv_mfma_kernel(
        const bf16* __restrict__ ypad,     // [b][130][132][256]
        const bf16* __restrict__ wq_r,     // [3][256][768]
        bf16* __restrict__ q) {            // [b][oc][hw]
    __shared__ __attribute__((aligned(16))) short Als[4096];
    __shared__ __attribute__((aligned(16))) short Bls[4096];
    int tid  = threadIdx.x;
    int y    = blockIdx.x;
    int oc0  = blockIdx.y * 128;
    int b    = blockIdx.z;
    int wave = tid >> 6, lane = tid & 63;
    int lm = lane & 15, kq = lane >> 4;

    f32x4 acc[2][8];
    #pragma unroll
    for (int mt = 0; mt < 2; mt++)
        #pragma unroll
        for (int nt = 0; nt < 8; nt++) acc[mt][nt] = (f32x4){0.f, 0.f, 0.f, 0.f};

    int s0 = tid, s1 = tid + 256;
    int r0 = s0 & 127, kq0 = s0 >> 7;
    int r1 = s1 & 127, kq1 = s1 >> 7;
    short* lA0 = &Als[(size_t)(wave * 64) * 8];
    short* lA1 = &Als[(size_t)(256 + wave * 64) * 8];
    short* lB0 = &Bls[(size_t)(wave * 64) * 8];
    short* lB1 = &Bls[(size_t)(256 + wave * 64) * 8];

    const short* wob = (const short*)wq_r + (size_t)oc0 * 768;
    const short* ybb = (const short*)ypad + (size_t)b * PBn;

    for (int dy = 0; dy < 3; dy++) {
        const short* wd = wob + (size_t)dy * Cn * 768;
        const short* yd = ybb + (size_t)(y + dy) * PROW;
        const short* wA0 = wd + (size_t)r0 * 768 + kq0 * 8;
        const short* wA1 = wd + (size_t)r1 * 768 + kq1 * 8;
        const short* yB0 = yd + (size_t)r0 * Cn + kq0 * 8;
        const short* yB1 = yd + (size_t)r1 * Cn + kq1 * 8;
        for (int kc = 0; kc < 768; kc += 32) {
            __syncthreads();
            gload16(wA0 + kc, lA0);
            gload16(wA1 + kc, lA1);
            gload16(yB0 + kc, lB0);
            gload16(yB1 + kc, lB1);
            __syncthreads();
            bf16x8 afr[2], bfr[8];
            #pragma unroll
            for (int mt = 0; mt < 2; mt++)
                afr[mt] = *(const bf16x8*)&Als[((kq << 7) + wave * 32 + mt * 16 + lm) * 8];
            #pragma unroll
            for (int nt = 0; nt < 8; nt++)
                bfr[nt] = *(const bf16x8*)&Bls[((kq << 7) + nt * 16 + lm) * 8];
            #pragma unroll
            for (int mt = 0; mt < 2; mt++)
                #pragma unroll
                for (int nt = 0; nt < 8; nt++)
                    acc[mt][nt] = __builtin_amdgcn_mfma_f32_16x16x32_bf16(
                        afr[mt], bfr[nt], acc[mt][nt], 0, 0, 0);
        }
    }
    bf16* qb = q + ((size_t)b * Cn + oc0) * HWn + (size_t)y * Wn;
    #pragma unroll
    for (int mt = 0; mt < 2; mt++) {
        int ocl = wave * 32 + mt * 16 + kq * 4;
        #pragma unroll
        for (int nt = 0; nt < 8; nt++) {
            int px = nt * 16 + lm;
            #pragma unroll
            for (int r = 0; r < 4; r++)
                qb[(size_t)(ocl + r) * HWn + px] = f2b(acc[mt][nt][r]);
        }
    }
}

// ---------------- per-row rsqrt(sumsq) scales for q and k ----------------
__global__ void norm_kernel(const bf16* __restrict__ q,
                            const bf16* __restrict__ kvdw,
                            float* __restrict__ qs,
                            float* __restrict__ ks) {
    int row = blockIdx.x;
    int b = row >> 8, c = row & 255;
    int tid = threadIdx.x;
    const bf16* src = (blockIdx.y == 0)
        ? q    + ((size_t)b * Cn  + c) * HWn
        : kvdw + ((size_t)b * C2n + c) * HWn;
    float ssum = 0.f;
    for (int i = tid; i < HWn; i += 256) {
        float v = b2f(src[i]);
        ssum += v * v;
    }
    __shared__ float red[256];
    red[tid] = ssum; __syncthreads();
    if (tid < 128) red[tid] += red[tid + 128];
    __syncthreads();
    if (tid < 64) red[tid] += red[tid + 64];
    __syncthreads();
    if (tid < 32) {
        float v = red[tid] + red[tid + 32];
        for (int off = 16; off > 0; off >>= 1) v += __shfl_xor(v, off);
        if (tid == 0) {
            float* dst = (blockIdx.y == 0) ? qs : ks;
            dst[row] = 1.f / fmaxf(sqrtf(v), 1e-12f);
        }
    }
}

// ---------------- QK^T partials via MFMA ----------------
__global__ __launch_bounds__(256) void attn_qk_kernel(
        const bf16* __restrict__ q,        // [b][c][hw]
        const bf16* __restrict__ kvdw,     // [b][2c][hw] (k = first half)
        float* __restrict__ partial) {     // [bh][split][32][32]
    __shared__ short qls[32 * 264];
    __shared__ short kls[32 * 264];
    __shared__ float sred[4][1024];
    int tid   = threadIdx.x;
    int split = blockIdx.x;                // 0..7
    int bh    = blockIdx.y;                // 0..31
    int b = bh >> 3, h = bh & 7;
    int wave = tid >> 6, lane = tid & 63;
    int lm = lane & 15, kq = lane >> 4;

    const short* qbase = (const short*)(q    + ((size_t)(b * Cn  + h * CHn)) * HWn) + split * 2048;
    const short* kbase = (const short*)(kvdw + ((size_t)(b * C2n + h * CHn)) * HWn) + split * 2048;

    f32x4 acc[2][2];
    #pragma unroll
    for (int mt = 0; mt < 2; mt++)
        #pragma unroll
        for (int nt = 0; nt < 2; nt++) acc[mt][nt] = (f32x4){0.f, 0.f, 0.f, 0.f};

    for (int n0 = 0; n0 < 2048; n0 += 256) {
        __syncthreads();
        for (int i = tid; i < 1024; i += 256) {
            int r = i >> 5, sg = (i & 31) * 8;
            *(bf16x8*)&qls[r * 264 + sg] = *(const bf16x8*)&qbase[(size_t)r * HWn + n0 + sg];
            *(bf16x8*)&kls[r * 264 + sg] = *(const bf16x8*)&kbase[(size_t)r * HWn + n0 + sg];
        }
        __syncthreads();
        int nb = wave * 64;
        #pragma unroll
        for (int kk = 0; kk < 64; kk += 32) {
            bf16x8 afr[2], bfr[2];
            #pragma unroll
            for (int mt = 0; mt < 2; mt++)
                afr[mt] = *(const bf16x8*)&qls[(mt * 16 + lm) * 264 + nb + kk + kq * 8];
            #pragma unroll
            for (int nt = 0; nt < 2; nt++)
                bfr[nt] = *(const bf16x8*)&kls[(nt * 16 + lm) * 264 + nb + kk + kq * 8];
            #pragma unroll
            for (int mt = 0; mt < 2; mt++)
                #pragma unroll
                for (int nt = 0; nt < 2; nt++)
                    acc[mt][nt] = __builtin_amdgcn_mfma_f32_16x16x32_bf16(
                        afr[mt], bfr[nt], acc[mt][nt], 0, 0, 0);
        }
    }
    __syncthreads();
    #pragma unroll
    for (int mt = 0; mt < 2; mt++)
        #pragma unroll
        for (int nt = 0; nt < 2; nt++)
            #pragma unroll
            for (int r = 0; r < 4; r++) {
                int c = mt * 16 + kq * 4 + r;
                int d = nt * 16 + lm;
                sred[wave][c * 32 + d] = acc[mt][nt][r];
            }
    __syncthreads();
    float* pb = partial + ((size_t)bh * 8 + split) * 1024;
    for (int i = tid; i < 1024; i += 256)
        pb[i] = sred[0][i] + sred[1][i] + sred[2][i] + sred[3][i];
}

// ---------------- reduce partials, scale, softmax ----------------
__global__ void attn_softmax_kernel(const float* __restrict__ partial,
                                    const float* __restrict__ qs,
                                    const float* __restrict__ ks,
                                    const float* __restrict__ temp,
                                    float* __restrict__ attn) {
    __shared__ float S[1024];
    int bh = blockIdx.x;
    int b = bh >> 3, h = bh & 7;
    int tid = threadIdx.x;
    for (int i = tid; i < 1024; i += 256) {
        float v = 0.f;
        #pragma unroll
        for (int sp = 0; sp < 8; sp++)
            v += partial[((size_t)bh * 8 + sp) * 1024 + i];
        int c = i >> 5, d = i & 31;
        v *= qs[b * Cn + h * CHn + c] * ks[b * Cn + h * CHn + d] * temp[h];
        S[i] = v;
    }
    __syncthreads();
    if (tid < 32) {
        int c = tid;
        float m = -1e30f;
        for (int d = 0; d < 32; d++) m = fmaxf(m, S[c * 32 + d]);
        float sum = 0.f;
        for (int d = 0; d < 32; d++) sum += __expf(S[c * 32 + d] - m);
        float inv = 1.f / sum;
        for (int d = 0; d < 32; d++)
            attn[(size_t)bh * 1024 + c * 32 + d] = __expf(S[c * 32 + d] - m) * inv;
    }
}

// ---------------- out = attn @ v  (writes PIXEL-MAJOR) ----------------
__global__ void av_kernel(const float* __restrict__ attn,
                          const bf16* __restrict__ kvdw,
                          bf16* __restrict__ ao_pm) {
    int bh = blockIdx.y;
    int b = bh >> 3, h = bh & 7;
    int tid = threadIdx.x;
    int n = blockIdx.x * 256 + tid;
    __shared__ float At[32][32];
    for (int i = tid; i < 1024; i += 256) {
        int cc = i >> 5, dd = i & 31;
        At[dd][cc] = attn[((size_t)bh * 32 + cc) * 32 + dd];
    }
    __syncthreads();
    const bf16* vbase = kvdw + ((size_t)b * C2n + Cn + h * CHn) * HWn;
    float acc[32];
    #pragma unroll
    for (int c = 0; c < 32; c++) acc[c] = 0.f;
    for (int d = 0; d < 32; d++) {
        float vv = b2f(vbase[(size_t)d * HWn + n]);
        #pragma unroll
        for (int c = 0; c < 32; c++) acc[c] += At[d][c] * vv;
    }
    bf16* obase = ao_pm + ((size_t)b * HWn + n) * Cn + h * CHn;
    #pragma unroll
    for (int g = 0; g < 4; g++) {
        bf16x8 v;
        #pragma unroll
        for (int j = 0; j < 8; j++) v[j] = f2bs(acc[g * 8 + j]);
        *(bf16x8*)&obase[g * 8] = v;
    }
}

// ---------------- proj 1x1 via MFMA + residual from padded yn ----------------
__global__ __launch_bounds__(256) void proj_mfma_kernel(
        const bf16* __restrict__ ao_pm,    // [b][px][c]
        const bf16* __restrict__ wpr_pk,   // [oc][c] bf16 (256x256)
        const bf16* __restrict__ ypad,     // [b][130][132][256] (residual)
        float* __restrict__ out) {         // [b][oc][px] f32
    __shared__ __attribute__((aligned(16))) short Als[4096];
    __shared__ __attribute__((aligned(16))) short Bls[4096];
    int tid  = threadIdx.x;
    int y    = blockIdx.x;                 // 128 px per block = one y row
    int px0  = y * 128;
    int oc0  = blockIdx.y * 128;
    int b    = blockIdx.z;
    int wave = tid >> 6, lane = tid & 63;
    int lm = lane & 15, kq = lane >> 4;

    f32x4 acc[2][8];
    #pragma unroll
    for (int mt = 0; mt < 2; mt++)
        #pragma unroll
        for (int nt = 0; nt < 8; nt++) acc[mt][nt] = (f32x4){0.f, 0.f, 0.f, 0.f};

    int s0 = tid, s1 = tid + 256;
    int r0 = s0 & 127, kq0 = s0 >> 7;
    int r1 = s1 & 127, kq1 = s1 >> 7;
    short* lA0 = &Als[(size_t)(wave * 64) * 8];
    short* lA1 = &Als[(size_t)(256 + wave * 64) * 8];
    short* lB0 = &Bls[(size_t)(wave * 64) * 8];
    short* lB1 = &Bls[(size_t)(256 + wave * 64) * 8];

    const short* wb = (const short*)wpr_pk + (size_t)oc0 * Cn;
    const short* ab = (const short*)(ao_pm) + ((size_t)b * HWn + px0) * Cn;
    const short* wA0 = wb + (size_t)r0 * Cn + kq0 * 8;
    const short* wA1 = wb + (size_t)r1 * Cn + kq1 * 8;
    const short* aB0 = ab + (size_t)r0 * Cn + kq0 * 8;
    const short* aB1 = ab + (size_t)r1 * Cn + kq1 * 8;

    for (int kc = 0; kc < Cn; kc += 32) {
        __syncthreads();
        gload16(wA0 + kc, lA0);
        gload16(wA1 + kc, lA1);
        gload16(aB0 + kc, lB0);
        gload16(aB1 + kc, lB1);
        __syncthreads();
        bf16x8 afr[2], bfr[8];
        #pragma unroll
        for (int mt = 0; mt < 2; mt++)
            afr[mt] = *(const bf16x8*)&Als[((kq << 7) + wave * 32 + mt * 16 + lm) * 8];
        #pragma unroll
        for (int nt = 0; nt < 8; nt++)
            bfr[nt] = *(const bf16x8*)&Bls[((kq << 7) + nt * 16 + lm) * 8];
        #pragma unroll
        for (int mt = 0; mt < 2; mt++)
            #pragma unroll
            for (int nt = 0; nt < 8; nt++)
                acc[mt][nt] = __builtin_amdgcn_mfma_f32_16x16x32_bf16(
                    afr[mt], bfr[nt], acc[mt][nt], 0, 0, 0);
    }
    const short* ynp = (const short*)ypad + (size_t)b * PBn
                     + ((size_t)(y + 1) * PADW + 1) * Cn;
    float* ob = out + ((size_t)b * Cn + oc0) * HWn + px0;
    #pragma unroll
    for (int mt = 0; mt < 2; mt++) {
        int ocl = wave * 32 + mt * 16 + kq * 4;
        #pragma unroll
        for (int nt = 0; nt < 8; nt++) {
            int px = nt * 16 + lm;
            #pragma unroll
            for (int r = 0; r < 4; r++)
                ob[(size_t)(ocl + r) * HWn + px] =
                    acc[mt][nt][r] + s2f(ynp[(size_t)px * Cn + oc0 + ocl + r]);
        }
    }
}

extern "C" void kernel_launch(void* const* d_in, const int* in_sizes, int n_in,
                              void* d_out, int out_size, void* d_ws, size_t ws_size,
                              hipStream_t stream) {
    const float* x     = (const float*)d_in[0];
    const float* y     = (const float*)d_in[1];
    const float* lnkw  = (const float*)d_in[2];
    const float* lnkb  = (const float*)d_in[3];
    const float* lnqw  = (const float*)d_in[4];
    const float* lnqb  = (const float*)d_in[5];
    const float* Wkv   = (const float*)d_in[6];
    const float* Wdw   = (const float*)d_in[7];
    const float* Wq    = (const float*)d_in[8];
    const float* Wproj = (const float*)d_in[9];
    const float* temp  = (const float*)d_in[10];
    float* out = (float*)d_out;

    char* ws = (char*)d_ws;
    const size_t TENB = (size_t)Bn * Cn * HWn * 2;     // 32 MiB (one bf16 tensor)
    // R0 [0, 64 MiB): xn_cm -> kv -> q_cm
    bf16* xn_cm = (bf16*)ws;
    bf16* kvb   = (bf16*)ws;
    bf16* q_cm  = (bf16*)ws;
    // R1 [64, 128 MiB): yn_cm -> kvdw
    bf16* yn_cm = (bf16*)(ws + 2 * TENB);
    bf16* kvdw  = (bf16*)(ws + 2 * TENB);
    // R2 [128, 160 MiB): xn_pm -> (partS) -> ao_pm
    bf16*  xn_pm = (bf16*)(ws + 4 * TENB);
    bf16*  ao_pm = xn_pm;
    float* partS = (float*)(ws + 4 * TENB);   // 1 MiB; xn_pm dead, read before ao written
    // R3 [160 MiB, +33.5 MiB): padded yn
    bf16* yn_pad = (bf16*)(ws + 5 * TENB);
    char* wp = ws + 5 * TENB + (size_t)Bn * PBn * 2;   // 35,143,680 B
    bf16* wq_r   = (bf16*)wp;  wp += (size_t)3 * Cn * 768 * 2;   // 1,179,648
    bf16* wkv_pk = (bf16*)wp;  wp += (size_t)C2n * Cn * 2;       //   262,144
    bf16* wpr_pk = (bf16*)wp;  wp += (size_t)Cn * Cn * 2;        //   131,072
    float* qs    = (float*)wp; wp += 4096;
    float* ksr   = (float*)wp; wp += 4096;
    float* attnP = (float*)wp; wp += 131072;

    // 0. weight preprocessing + halo zero
    wq_repack_kernel<<<dim3(256), 256, 0, stream>>>(Wq, wq_r);
    cast_kernel<<<dim3(128), 256, 0, stream>>>(Wkv, wkv_pk, C2n * Cn);
    cast_kernel<<<dim3(64), 256, 0, stream>>>(Wproj, wpr_pk, Cn * Cn);
    halo_zero_kernel<<<dim3(PADH, Bn), 256, 0, stream>>>(yn_pad);
    // 1-2. LayerNorms (channel-major bf16)
    ln_kernel<<<dim3(Bn * HWn / 256), 256, 0, stream>>>(x, lnkw, lnkb, xn_cm);
    ln_kernel<<<dim3(Bn * HWn / 256), 256, 0, stream>>>(y, lnqw, lnqb, yn_cm);
    // 3-4. transposes to pixel-major (yn goes into padded layout)
    transpose_kernel<<<dim3(HWn / 64, Cn / 64, Bn), 256, 0, stream>>>(xn_cm, xn_pm);
    transpose_pad_kernel<<<dim3(HWn / 64, Cn / 64, Bn), 256, 0, stream>>>(yn_cm, yn_pad);
    // 5. kv = 1x1 conv via MFMA (overwrites xn_cm — dead)
    kv1x1_mfma_kernel<<<dim3(HWn / 128, C2n / 128, Bn), 256, 0, stream>>>(xn_pm, wkv_pk, kvb);
    // 6. depthwise 3x3 -> kvdw (overwrites yn_cm — dead)
    dw_kernel<<<dim3(Hn / 16, C2n, Bn), 256, 0, stream>>>(kvb, Wdw, kvdw);
    // 7. q = 3x3 conv as 3 contiguous-K row-GEMMs -> q_cm (kv dead after dw)
    qconv_mfma_kernel<<<dim3(Hn, Cn / 128, Bn), 256, 0, stream>>>(yn_pad, wq_r, q_cm);
    // 8. L2-norm scales
    norm_kernel<<<dim3(Bn * Cn, 2), 256, 0, stream>>>(q_cm, kvdw, qs, ksr);
    // 9a. QK^T partials via MFMA
    attn_qk_kernel<<<dim3(8, Bn * HEADSn), 256, 0, stream>>>(q_cm, kvdw, partS);
    // 9b. reduce + scale + softmax
    attn_softmax_kernel<<<dim3(Bn * HEADSn), 256, 0, stream>>>(partS, qs, ksr, temp, attnP);
    // 10. attn @ v -> ao_pm (xn_pm dead, partS consumed)
    av_kernel<<<dim3(HWn / 256, Bn * HEADSn), 256, 0, stream>>>(attnP, kvdw, ao_pm);
    // 11. proj 1x1 via MFMA + residual -> final f32 output
    proj_mfma_kernel<<<dim3(HWn / 128, Cn / 128, Bn), 256, 0, stream>>>(ao_pm, wpr_pk, yn_pad, out);
}